// Round 15
// baseline (239.529 us; speedup 1.0000x reference)
//
#include <hip/hip_runtime.h>
#include <hip/hip_bf16.h>

using bf16 = __hip_bfloat16;
typedef __attribute__((ext_vector_type(8))) short short8;
typedef __attribute__((ext_vector_type(4))) float f32x4;
typedef __attribute__((ext_vector_type(4))) unsigned int u32x4;

__device__ __forceinline__ float b2f(bf16 x){ return __bfloat162float(x); }
__device__ __forceinline__ bf16  f2b(float x){ return __float2bfloat16(x); }
__device__ __forceinline__ float e2(float x){ return __builtin_amdgcn_exp2f(x); }
__device__ __forceinline__ unsigned pk2(float lo, float hi){
  return (unsigned)__bfloat16_as_ushort(f2b(lo)) | ((unsigned)__bfloat16_as_ushort(f2b(hi))<<16);
}

__device__ __forceinline__ void gload_lds16(const void* g, void* l){
  __builtin_amdgcn_global_load_lds((const __attribute__((address_space(1))) unsigned int*)g,
                                   (__attribute__((address_space(3))) unsigned int*)l, 16, 0, 0);
}

// ---------------- transpose f32 [R,C] -> bf16 [C,R] ----------------
__global__ __launch_bounds__(256) void transpose_k(const float* __restrict__ in,
                                                   bf16* __restrict__ out, int R, int C){
  __shared__ bf16 tile[32][33];
  int bx = blockIdx.x*32, by = blockIdx.y*32;
  int tx = threadIdx.x, ty = threadIdx.y;
  #pragma unroll
  for (int i=0;i<32;i+=8) tile[ty+i][tx] = f2b(in[(size_t)(by+ty+i)*C + bx+tx]);
  __syncthreads();
  #pragma unroll
  for (int i=0;i<32;i+=8) out[(size_t)(bx+ty+i)*R + by+tx] = tile[tx][ty+i];
}

// ---------------- V transpose: qkvV[b*2048+n][ld] (h*64+d cols) -> vT[(b*16+h)*64+d][2048] ----------------
__global__ __launch_bounds__(256) void vtrans_k(const bf16* __restrict__ in, bf16* __restrict__ out, int ld){
  __shared__ bf16 tile[32][33];
  int bh = blockIdx.z, b = bh>>4, h = bh&15;
  int bn = blockIdx.x*32, bd = blockIdx.y*32;
  int tx = threadIdx.x, ty = threadIdx.y;
  #pragma unroll
  for (int i=0;i<32;i+=8)
    tile[ty+i][tx] = in[(size_t)(b*2048 + bn+ty+i)*ld + h*64 + bd+tx];
  __syncthreads();
  #pragma unroll
  for (int i=0;i<32;i+=8)
    out[(size_t)(bh*64 + bd+ty+i)*2048 + bn+tx] = tile[tx][ty+i];
}

// ---------------- layernorm: row of 1024 f32 -> bf16, block=256 ----------------
__global__ __launch_bounds__(256) void ln_k(const float* __restrict__ in, const float* __restrict__ w,
                                            const float* __restrict__ b, bf16* __restrict__ out){
  int row = blockIdx.x, t = threadIdx.x;
  const float* rp = in + (size_t)row*1024;
  float xv[4]; float s = 0.f, s2 = 0.f;
  #pragma unroll
  for (int j=0;j<4;++j){ float x = rp[t + j*256]; xv[j]=x; s+=x; s2+=x*x; }
  #pragma unroll
  for (int d=1; d<64; d<<=1){ s += __shfl_xor(s,d,64); s2 += __shfl_xor(s2,d,64); }
  __shared__ float sb[8];
  if ((t&63)==0){ sb[t>>6]=s; sb[4+(t>>6)]=s2; }
  __syncthreads();
  s = sb[0]+sb[1]+sb[2]+sb[3]; s2 = sb[4]+sb[5]+sb[6]+sb[7];
  float mu = s*(1.f/1024.f);
  float var = s2*(1.f/1024.f) - mu*mu;
  float rs = rsqrtf(var + 1e-5f);
  #pragma unroll
  for (int j=0;j<4;++j){
    int c = t + j*256;
    out[(size_t)row*1024 + c] = f2b((xv[j]-mu)*rs*w[c] + b[c]);
  }
}

// ---------------- big GEMM: 256x256 tile, BK=32, 4-deep LDS ring, counted vmcnt, XOR-swizzled LDS ----------------
// EPI: 0 = bias, first 1024 cols scaled by SC2 (QKV, pre-scales Q) -> bf16 ; 1 = bias+GELU(tanh-form) -> bf16
template<int EPI>
__global__ __launch_bounds__(512,2) void gemm256(const bf16* __restrict__ A, const bf16* __restrict__ Bt,
                                                 const float* __restrict__ bias, bf16* __restrict__ Cp,
                                                 int M, int N, int K){
  extern __shared__ char lds[];
  const int t = threadIdx.x, lane = t & 63, w = t >> 6;
  const int wm = w >> 2, wn = w & 3;
  const int lrow = lane & 15, g = lane >> 4;
  const int sw = (lrow & 7) << 4;

  const int nwg = gridDim.x;
  int flat = blockIdx.x;
  int nb = (nwg & 7) ? flat : ((flat & 7)*(nwg>>3) + (flat>>3));
  const int nbx = N >> 8;
  const int bm = (nb / nbx) << 8, bn = (nb % nbx) << 8;

  f32x4 acc[8][4] = {};
  const int nt = K >> 5;

  int srcOff[2];
  #pragma unroll
  for (int i=0;i<2;++i){
    int p = t + i*512;
    int r = ((p>>3)<<1) | (((p>>2)&1) ^ ((p>>4)&1));
    int gc = ((((p>>1)&1) ^ ((p>>3)&1))<<1) | ((p&1) ^ ((p>>2)&1) ^ ((p>>4)&1));
    srcOff[i] = r*K + gc*8;
  }

  auto STAGE = [&](int tt){
    char* sA = lds + (size_t)(tt&3)*32768;
    char* sB = sA + 16384;
    int k0 = tt << 5;
    #pragma unroll
    for (int i=0;i<2;++i){
      unsigned dst = (unsigned)(i*8192 + w*1024);
      gload_lds16(A  + (size_t)bm*K + srcOff[i] + k0, sA + dst);
      gload_lds16(Bt + (size_t)bn*K + srcOff[i] + k0, sB + dst);
    }
  };

  auto COMPUTE = [&](int tt){
    const char* sA = lds + (size_t)(tt&3)*32768;
    const char* sB = sA + 16384;
    short8 af[8], bfr[4];
    #pragma unroll
    for (int mf=0;mf<8;++mf)
      af[mf] = *(const short8*)(sA + (((wm*128 + mf*16 + lrow)*64 + g*16) ^ sw));
    #pragma unroll
    for (int nf=0;nf<4;++nf)
      bfr[nf] = *(const short8*)(sB + (((wn*64 + nf*16 + lrow)*64 + g*16) ^ sw));
    __builtin_amdgcn_s_setprio(1);
    #pragma unroll
    for (int mf=0;mf<8;++mf)
      #pragma unroll
      for (int nf=0;nf<4;++nf)
        acc[mf][nf] = __builtin_amdgcn_mfma_f32_16x16x32_bf16(af[mf], bfr[nf], acc[mf][nf], 0,0,0);
    __builtin_amdgcn_s_setprio(0);
  };

  STAGE(0); STAGE(1); STAGE(2);
  asm volatile("s_waitcnt vmcnt(8)" ::: "memory");
  __builtin_amdgcn_s_barrier();

  for (int tt=0; tt<nt-3; ++tt){
    STAGE(tt+3);
    COMPUTE(tt);
    asm volatile("s_waitcnt vmcnt(8)" ::: "memory");
    __builtin_amdgcn_s_barrier();
  }
  COMPUTE(nt-3);
  asm volatile("s_waitcnt vmcnt(4)" ::: "memory");
  __builtin_amdgcn_s_barrier();
  COMPUTE(nt-2);
  asm volatile("s_waitcnt vmcnt(0)" ::: "memory");
  __builtin_amdgcn_s_barrier();
  COMPUTE(nt-1);

  const float SC2 = 0.125f * 1.44269504089f;
  #pragma unroll
  for (int mf=0;mf<8;++mf){
    int rowb = bm + wm*128 + mf*16 + g*4;
    #pragma unroll
    for (int nf=0;nf<4;++nf){
      int col = bn + wn*64 + nf*16 + lrow;
      float bv = bias[col];
      #pragma unroll
      for (int r=0;r<4;++r){
        float vv = acc[mf][nf][r] + bv;
        if constexpr (EPI==0){ if (col < 1024) vv *= SC2; }
        if constexpr (EPI==1){
          float ex = e2(-2.3022080654f*(vv + 0.044715f*vv*vv*vv));
          vv = vv * __builtin_amdgcn_rcpf(1.0f + ex);
        }
        Cp[(size_t)(rowb+r)*N + col] = f2b(vv);
      }
    }
  }
}

// ---------------- mid GEMM v2: 128x64 tile, BK=32, 4-deep ring (48KB -> 2 blocks/CU), counted vmcnt ----------------
// For N=1024 shapes (proj, MLP2): grid 512 = 2 blocks/CU. EPI: 2 = bias + f32 residual -> f32 out.
// 4 waves (2M x 2N), per-wave 64x32 output, acc[4][2]. Ledger: 3 loads/stage, 3 stages in flight -> vmcnt 6/3/0.
template<int EPI>
__global__ __launch_bounds__(256,2) void gemm128(const bf16* __restrict__ A, const bf16* __restrict__ Bt,
                                                 const float* __restrict__ bias, const float* __restrict__ res,
                                                 void* __restrict__ Cp, int M, int N, int K){
  extern __shared__ char lds[];
  const int t = threadIdx.x, lane = t & 63, w = t >> 6;
  const int wm = w >> 1, wn = w & 1;
  const int lrow = lane & 15, g = lane >> 4;
  const int sw = (lrow & 7) << 4;

  const int nwg = gridDim.x;
  int flat = blockIdx.x;
  int nb = (nwg & 7) ? flat : ((flat & 7)*(nwg>>3) + (flat>>3));
  const int nbx = N >> 6;
  const int bm = (nb / nbx) << 7, bn = (nb % nbx) << 6;

  f32x4 acc[4][2] = {};
  const int nt = K >> 5;

  // inverse of the 64B-row swizzle: unit p -> (row r, unit-col gc)
  int srcOffA[2], srcOffB;
  #pragma unroll
  for (int i=0;i<2;++i){
    int p = t + i*256;
    int r = ((p>>3)<<1) | (((p>>2)&1) ^ ((p>>4)&1));
    int gc = ((((p>>1)&1) ^ ((p>>3)&1))<<1) | ((p&1) ^ ((p>>2)&1) ^ ((p>>4)&1));
    srcOffA[i] = r*K + gc*8;
  }
  {
    int p = t;
    int r = ((p>>3)<<1) | (((p>>2)&1) ^ ((p>>4)&1));
    int gc = ((((p>>1)&1) ^ ((p>>3)&1))<<1) | ((p&1) ^ ((p>>2)&1) ^ ((p>>4)&1));
    srcOffB = r*K + gc*8;
  }

  auto STAGE = [&](int tt){
    char* sA = lds + (size_t)(tt&3)*12288;   // slot: 8KB A + 4KB B
    char* sB = sA + 8192;
    int k0 = tt << 5;
    #pragma unroll
    for (int i=0;i<2;++i)
      gload_lds16(A + (size_t)bm*K + srcOffA[i] + k0, sA + (unsigned)(i*4096 + w*1024));
    gload_lds16(Bt + (size_t)bn*K + srcOffB + k0, sB + (unsigned)(w*1024));
  };

  auto COMPUTE = [&](int tt){
    const char* sA = lds + (size_t)(tt&3)*12288;
    const char* sB = sA + 8192;
    short8 af[4], bfr[2];
    #pragma unroll
    for (int mf=0;mf<4;++mf)
      af[mf] = *(const short8*)(sA + (((wm*64 + mf*16 + lrow)*64 + g*16) ^ sw));
    #pragma unroll
    for (int nf=0;nf<2;++nf)
      bfr[nf] = *(const short8*)(sB + (((wn*32 + nf*16 + lrow)*64 + g*16) ^ sw));
    __builtin_amdgcn_s_setprio(1);
    #pragma unroll
    for (int mf=0;mf<4;++mf)
      #pragma unroll
      for (int nf=0;nf<2;++nf)
        acc[mf][nf] = __builtin_amdgcn_mfma_f32_16x16x32_bf16(af[mf], bfr[nf], acc[mf][nf], 0,0,0);
    __builtin_amdgcn_s_setprio(0);
  };

  STAGE(0); STAGE(1); STAGE(2);
  asm volatile("s_waitcnt vmcnt(6)" ::: "memory");
  __builtin_amdgcn_s_barrier();

  for (int tt=0; tt<nt-3; ++tt){
    STAGE(tt+3);
    COMPUTE(tt);
    asm volatile("s_waitcnt vmcnt(6)" ::: "memory");
    __builtin_amdgcn_s_barrier();
  }
  COMPUTE(nt-3);
  asm volatile("s_waitcnt vmcnt(3)" ::: "memory");
  __builtin_amdgcn_s_barrier();
  COMPUTE(nt-2);
  asm volatile("s_waitcnt vmcnt(0)" ::: "memory");
  __builtin_amdgcn_s_barrier();
  COMPUTE(nt-1);

  #pragma unroll
  for (int mf=0;mf<4;++mf){
    int rowb = bm + wm*64 + mf*16 + g*4;
    #pragma unroll
    for (int nf=0;nf<2;++nf){
      int col = bn + wn*32 + nf*16 + lrow;
      float bv = bias[col];
      #pragma unroll
      for (int r=0;r<4;++r){
        size_t idx = (size_t)(rowb+r)*N + col;
        float vv = acc[mf][nf][r] + bv;
        if constexpr (EPI==2){ vv += res[idx]; ((float*)Cp)[idx] = vv; }
        else ((bf16*)Cp)[idx] = f2b(vv);
      }
    }
  }
}

// ---------------- flash attention v8: swapped QK^T, STATIC softmax (m=0), in-reg P exchange ----------------
__global__ __launch_bounds__(512,4) void attn_k(const bf16* __restrict__ q, const bf16* __restrict__ k,
                                                const bf16* __restrict__ vT, bf16* __restrict__ o, int ldq){
  __shared__ char Ks[2][8192];
  __shared__ char Vs[2][8192];

  int flat = blockIdx.x;
  int xs = flat & 7, j = flat >> 3;
  int bh = xs*4 + (j & 3), qt = j >> 2;
  int b = bh >> 4, h = bh & 15;
  int t = threadIdx.x, lane = t & 63, w = t >> 6;
  int lrow = lane & 15, g = lane >> 4, lko = g*8;

  const bf16* kbase = k  + (size_t)b*2048*ldq + h*64;
  const bf16* vtb   = vT + (size_t)bh*64*2048;

  size_t qrow = (size_t)(b*2048 + qt*128 + w*16 + lrow);
  short8 qf0 = *(const short8*)(q + qrow*ldq + h*64 + lko);
  short8 qf1 = *(const short8*)(q + qrow*ldq + h*64 + 32 + lko);

  int srow = t >> 3, scolb = (t & 7) << 4;
  int ssw = scolb ^ ((srow & 7) << 4);
  const bf16* ksrc = kbase + (size_t)srow*ldq + (ssw >> 1);
  const bf16* vsrc = vtb   + (size_t)srow*2048 + (ssw >> 1);
  unsigned ldst = (unsigned)(w*64*16);

  const short8 onesf = {0x3F80,0x3F80,0x3F80,0x3F80,0x3F80,0x3F80,0x3F80,0x3F80};

  const int srcU = lrow + ((2*(g&1) + (g>>1)) << 4);
  const int srcV = lrow + ((2*(g&1) + 1 - (g>>1)) << 4);
  const bool gOdd = (g & 1), lo = ((g>>1) == 0);

  f32x4 lacc = {};
  f32x4 oacc[4] = {};
  const int sw = (lrow & 7) << 4;

  gload_lds16(ksrc, Ks[0] + ldst);
  gload_lds16(vsrc, Vs[0] + ldst);
  __syncthreads();

  int cur = 0;
  for (int tile = 0; tile < 32; ++tile){
    int kt = tile*64;
    if (tile < 31){
      gload_lds16(ksrc + (size_t)(kt+64)*ldq, Ks[cur^1] + ldst);
      gload_lds16(vsrc + (kt+64),             Vs[cur^1] + ldst);
    }

    f32x4 s[4];
    __builtin_amdgcn_s_setprio(1);
    #pragma unroll
    for (int cb=0; cb<4; ++cb){
      const char* kp = Ks[cur] + (cb*16 + lrow)*128;
      short8 kf0 = *(const short8*)(kp + ((g*16) ^ sw));
      short8 kf1 = *(const short8*)(kp + ((64 + g*16) ^ sw));
      f32x4 a = {};
      a = __builtin_amdgcn_mfma_f32_16x16x32_bf16(kf0, qf0, a, 0,0,0);
      a = __builtin_amdgcn_mfma_f32_16x16x32_bf16(kf1, qf1, a, 0,0,0);
      s[cb] = a;
    }
    __builtin_amdgcn_s_setprio(0);

    // static softmax: P = exp2(s), no running max, no rescale
    unsigned pA0 = pk2(e2(s[0][0]), e2(s[0][1]));
    unsigned pB0 = pk2(e2(s[0][2]), e2(s[0][3]));
    unsigned pA1 = pk2(e2(s[1][0]), e2(s[1][1]));
    unsigned pB1 = pk2(e2(s[1][2]), e2(s[1][3]));
    unsigned pA2 = pk2(e2(s[2][0]), e2(s[2][1]));
    unsigned pB2 = pk2(e2(s[2][2]), e2(s[2][3]));
    unsigned pA3 = pk2(e2(s[3][0]), e2(s[3][1]));
    unsigned pB3 = pk2(e2(s[3][2]), e2(s[3][3]));

    unsigned ruA = __shfl((int)(gOdd?pA1:pA0), srcU, 64);
    unsigned rvA = __shfl((int)(gOdd?pA0:pA1), srcV, 64);
    unsigned ruB = __shfl((int)(gOdd?pB1:pB0), srcU, 64);
    unsigned rvB = __shfl((int)(gOdd?pB0:pB1), srcV, 64);
    unsigned ruA2= __shfl((int)(gOdd?pA3:pA2), srcU, 64);
    unsigned rvA2= __shfl((int)(gOdd?pA2:pA3), srcV, 64);
    unsigned ruB2= __shfl((int)(gOdd?pB3:pB2), srcU, 64);
    unsigned rvB2= __shfl((int)(gOdd?pB2:pB3), srcV, 64);

    u32x4 w0 = { lo?ruA:rvA,  lo?ruB:rvB,  lo?rvA:ruA,  lo?rvB:ruB  };
    u32x4 w1 = { lo?ruA2:rvA2,lo?ruB2:rvB2,lo?rvA2:ruA2,lo?rvB2:ruB2};
    short8 pf0 = __builtin_bit_cast(short8, w0);
    short8 pf1 = __builtin_bit_cast(short8, w1);

    __builtin_amdgcn_s_setprio(1);
    lacc = __builtin_amdgcn_mfma_f32_16x16x32_bf16(pf0, onesf, lacc, 0,0,0);
    lacc = __builtin_amdgcn_mfma_f32_16x16x32_bf16(pf1, onesf, lacc, 0,0,0);
    #pragma unroll
    for (int half=0; half<2; ++half){
      short8 pf = half ? pf1 : pf0;
      #pragma unroll
      for (int db=0; db<4; ++db){
        const char* vp = Vs[cur] + (db*16 + lrow)*128;
        short8 vf = *(const short8*)(vp + ((half*64 + g*16) ^ sw));
        oacc[db] = __builtin_amdgcn_mfma_f32_16x16x32_bf16(pf, vf, oacc[db], 0,0,0);
      }
    }
    __builtin_amdgcn_s_setprio(0);
    __syncthreads();
    cur ^= 1;
  }

  f32x4 inv;
  #pragma unroll
  for (int r=0;r<4;++r) inv[r] = 1.0f/lacc[r];
  size_t obase = ((size_t)(b*2048 + qt*128 + w*16))*1024 + h*64;
  #pragma unroll
  for (int db=0; db<4; ++db)
    #pragma unroll
    for (int r=0;r<4;++r)
      o[obase + (size_t)(g*4+r)*1024 + db*16 + lrow] = f2b(oacc[db][r] * inv[r]);
}

// ---------------- launch ----------------
extern "C" void kernel_launch(void* const* d_in, const int* in_sizes, int n_in,
                              void* d_out, int out_size, void* d_ws, size_t ws_size,
                              hipStream_t stream) {
  (void)in_sizes; (void)n_in; (void)out_size; (void)ws_size;
  const float* x    = (const float*)d_in[0];
  const float* ln1w = (const float*)d_in[1];
  const float* ln1b = (const float*)d_in[2];
  const float* ln2w = (const float*)d_in[3];
  const float* ln2b = (const float*)d_in[4];
  const float* wq   = (const float*)d_in[5];
  const float* bq   = (const float*)d_in[6];
  const float* wk   = (const float*)d_in[7];
  const float* bk   = (const float*)d_in[8];
  const float* wv   = (const float*)d_in[9];
  const float* bv   = (const float*)d_in[10];
  const float* wo   = (const float*)d_in[11];
  const float* bo   = (const float*)d_in[12];
  const float* w1   = (const float*)d_in[13];
  const float* b1   = (const float*)d_in[14];
  const float* w2   = (const float*)d_in[15];
  const float* b2   = (const float*)d_in[16];

  char* ws = (char*)d_ws;
  const size_t MB = 1u<<20;
  bf16* wqkvT = (bf16*)(ws + 0*MB);   // [3072,1024] bf16
  bf16* woT   = (bf16*)(ws + 6*MB);
  bf16* w1T   = (bf16*)(ws + 8*MB);   // [4096,1024]
  bf16* w2T   = (bf16*)(ws + 16*MB);  // [1024,4096]
  bf16* qkv   = (bf16*)(ws + 24*MB);  // [4096,3072] bf16 = 24 MB
  bf16* ao    = (bf16*)(ws + 48*MB);  // [4096,1024] bf16 = 8 MB
  bf16* vT    = (bf16*)(ws + 56*MB);  // 8 MB, alive only during attn
  float* x1   = (float*)(ws + 56*MB); // 16 MB f32, written after attn
  bf16* lnb   = (bf16*)(ws + 72*MB);  // 8 MB
  bf16* h1    = (bf16*)(ws + 24*MB);  // [4096,4096] bf16 = 32 MB, reuse qkv+ao after proj
  float* bqkv = (float*)(ws + 80*MB); // 12 KB

  hipMemcpyAsync(bqkv,        bq, 1024*sizeof(float), hipMemcpyDeviceToDevice, stream);
  hipMemcpyAsync(bqkv + 1024, bk, 1024*sizeof(float), hipMemcpyDeviceToDevice, stream);
  hipMemcpyAsync(bqkv + 2048, bv, 1024*sizeof(float), hipMemcpyDeviceToDevice, stream);

  dim3 tpb(32,8);
  transpose_k<<<dim3(32,32),  tpb,0,stream>>>(wq, wqkvT,            1024,1024);
  transpose_k<<<dim3(32,32),  tpb,0,stream>>>(wk, wqkvT + 1024*1024,1024,1024);
  transpose_k<<<dim3(32,32),  tpb,0,stream>>>(wv, wqkvT + 2048*1024,1024,1024);
  transpose_k<<<dim3(32,32),  tpb,0,stream>>>(wo, woT, 1024,1024);
  transpose_k<<<dim3(128,32), tpb,0,stream>>>(w1, w1T, 1024,4096);
  transpose_k<<<dim3(32,128), tpb,0,stream>>>(w2, w2T, 4096,1024);

  ln_k<<<4096,256,0,stream>>>(x, ln1w, ln1b, lnb);
  gemm256<0><<<192,512,131072,stream>>>(lnb, wqkvT, bqkv, qkv, 4096,3072,1024);
  vtrans_k<<<dim3(64,2,32),tpb,0,stream>>>(qkv + 2048, vT, 3072);
  attn_k<<<512,512,0,stream>>>(qkv, qkv + 1024, vT, ao, 3072);
  gemm128<2><<<512,256,49152,stream>>>(ao, woT, bo, x, x1, 4096,1024,1024);
  ln_k<<<4096,256,0,stream>>>(x1, ln2w, ln2b, lnb);
  gemm256<1><<<256,512,131072,stream>>>(lnb, w1T, b1, h1, 4096,4096,1024);
  gemm128<2><<<512,256,49152,stream>>>(h1, w2T, b2, x1, (float*)d_out, 4096,1024,4096);
}

// Round 16
// 224.439 us; speedup vs baseline: 1.0672x; 1.0672x over previous
//
#include <hip/hip_runtime.h>
#include <hip/hip_bf16.h>

using bf16 = __hip_bfloat16;
typedef __attribute__((ext_vector_type(8))) short short8;
typedef __attribute__((ext_vector_type(4))) float f32x4;
typedef __attribute__((ext_vector_type(4))) unsigned int u32x4;

__device__ __forceinline__ float b2f(bf16 x){ return __bfloat162float(x); }
__device__ __forceinline__ bf16  f2b(float x){ return __float2bfloat16(x); }
__device__ __forceinline__ float e2(float x){ return __builtin_amdgcn_exp2f(x); }
__device__ __forceinline__ unsigned pk2(float lo, float hi){
  return (unsigned)__bfloat16_as_ushort(f2b(lo)) | ((unsigned)__bfloat16_as_ushort(f2b(hi))<<16);
}

__device__ __forceinline__ void gload_lds16(const void* g, void* l){
  __builtin_amdgcn_global_load_lds((const __attribute__((address_space(1))) unsigned int*)g,
                                   (__attribute__((address_space(3))) unsigned int*)l, 16, 0, 0);
}

// ---------------- transpose f32 [R,C] -> bf16 [C,R] ----------------
__global__ __launch_bounds__(256) void transpose_k(const float* __restrict__ in,
                                                   bf16* __restrict__ out, int R, int C){
  __shared__ bf16 tile[32][33];
  int bx = blockIdx.x*32, by = blockIdx.y*32;
  int tx = threadIdx.x, ty = threadIdx.y;
  #pragma unroll
  for (int i=0;i<32;i+=8) tile[ty+i][tx] = f2b(in[(size_t)(by+ty+i)*C + bx+tx]);
  __syncthreads();
  #pragma unroll
  for (int i=0;i<32;i+=8) out[(size_t)(bx+ty+i)*R + by+tx] = tile[tx][ty+i];
}

// ---------------- V transpose: qkvV[b*2048+n][ld] (h*64+d cols) -> vT[(b*16+h)*64+d][2048] ----------------
__global__ __launch_bounds__(256) void vtrans_k(const bf16* __restrict__ in, bf16* __restrict__ out, int ld){
  __shared__ bf16 tile[32][33];
  int bh = blockIdx.z, b = bh>>4, h = bh&15;
  int bn = blockIdx.x*32, bd = blockIdx.y*32;
  int tx = threadIdx.x, ty = threadIdx.y;
  #pragma unroll
  for (int i=0;i<32;i+=8)
    tile[ty+i][tx] = in[(size_t)(b*2048 + bn+ty+i)*ld + h*64 + bd+tx];
  __syncthreads();
  #pragma unroll
  for (int i=0;i<32;i+=8)
    out[(size_t)(bh*64 + bd+ty+i)*2048 + bn+tx] = tile[tx][ty+i];
}

// ---------------- layernorm: row of 1024 f32 -> bf16, block=256 ----------------
__global__ __launch_bounds__(256) void ln_k(const float* __restrict__ in, const float* __restrict__ w,
                                            const float* __restrict__ b, bf16* __restrict__ out){
  int row = blockIdx.x, t = threadIdx.x;
  const float* rp = in + (size_t)row*1024;
  float xv[4]; float s = 0.f, s2 = 0.f;
  #pragma unroll
  for (int j=0;j<4;++j){ float x = rp[t + j*256]; xv[j]=x; s+=x; s2+=x*x; }
  #pragma unroll
  for (int d=1; d<64; d<<=1){ s += __shfl_xor(s,d,64); s2 += __shfl_xor(s2,d,64); }
  __shared__ float sb[8];
  if ((t&63)==0){ sb[t>>6]=s; sb[4+(t>>6)]=s2; }
  __syncthreads();
  s = sb[0]+sb[1]+sb[2]+sb[3]; s2 = sb[4]+sb[5]+sb[6]+sb[7];
  float mu = s*(1.f/1024.f);
  float var = s2*(1.f/1024.f) - mu*mu;
  float rs = rsqrtf(var + 1e-5f);
  #pragma unroll
  for (int j=0;j<4;++j){
    int c = t + j*256;
    out[(size_t)row*1024 + c] = f2b((xv[j]-mu)*rs*w[c] + b[c]);
  }
}

// ---------------- big GEMM: 256x256 tile, BK=32, 4-deep LDS ring, counted vmcnt, XOR-swizzled LDS ----------------
// EPI: 0 = bias, first 1024 cols scaled by SC2 (QKV, pre-scales Q) -> bf16 ; 1 = bias+GELU(tanh-form) -> bf16
template<int EPI>
__global__ __launch_bounds__(512,2) void gemm256(const bf16* __restrict__ A, const bf16* __restrict__ Bt,
                                                 const float* __restrict__ bias, bf16* __restrict__ Cp,
                                                 int M, int N, int K){
  extern __shared__ char lds[];
  const int t = threadIdx.x, lane = t & 63, w = t >> 6;
  const int wm = w >> 2, wn = w & 3;
  const int lrow = lane & 15, g = lane >> 4;
  const int sw = (lrow & 7) << 4;

  const int nwg = gridDim.x;
  int flat = blockIdx.x;
  int nb = (nwg & 7) ? flat : ((flat & 7)*(nwg>>3) + (flat>>3));
  const int nbx = N >> 8;
  const int bm = (nb / nbx) << 8, bn = (nb % nbx) << 8;

  f32x4 acc[8][4] = {};
  const int nt = K >> 5;

  int srcOff[2];
  #pragma unroll
  for (int i=0;i<2;++i){
    int p = t + i*512;
    int r = ((p>>3)<<1) | (((p>>2)&1) ^ ((p>>4)&1));
    int gc = ((((p>>1)&1) ^ ((p>>3)&1))<<1) | ((p&1) ^ ((p>>2)&1) ^ ((p>>4)&1));
    srcOff[i] = r*K + gc*8;
  }

  auto STAGE = [&](int tt){
    char* sA = lds + (size_t)(tt&3)*32768;
    char* sB = sA + 16384;
    int k0 = tt << 5;
    #pragma unroll
    for (int i=0;i<2;++i){
      unsigned dst = (unsigned)(i*8192 + w*1024);
      gload_lds16(A  + (size_t)bm*K + srcOff[i] + k0, sA + dst);
      gload_lds16(Bt + (size_t)bn*K + srcOff[i] + k0, sB + dst);
    }
  };

  auto COMPUTE = [&](int tt){
    const char* sA = lds + (size_t)(tt&3)*32768;
    const char* sB = sA + 16384;
    short8 af[8], bfr[4];
    #pragma unroll
    for (int mf=0;mf<8;++mf)
      af[mf] = *(const short8*)(sA + (((wm*128 + mf*16 + lrow)*64 + g*16) ^ sw));
    #pragma unroll
    for (int nf=0;nf<4;++nf)
      bfr[nf] = *(const short8*)(sB + (((wn*64 + nf*16 + lrow)*64 + g*16) ^ sw));
    __builtin_amdgcn_s_setprio(1);
    #pragma unroll
    for (int mf=0;mf<8;++mf)
      #pragma unroll
      for (int nf=0;nf<4;++nf)
        acc[mf][nf] = __builtin_amdgcn_mfma_f32_16x16x32_bf16(af[mf], bfr[nf], acc[mf][nf], 0,0,0);
    __builtin_amdgcn_s_setprio(0);
  };

  STAGE(0); STAGE(1); STAGE(2);
  asm volatile("s_waitcnt vmcnt(8)" ::: "memory");
  __builtin_amdgcn_s_barrier();

  for (int tt=0; tt<nt-3; ++tt){
    STAGE(tt+3);
    COMPUTE(tt);
    asm volatile("s_waitcnt vmcnt(8)" ::: "memory");
    __builtin_amdgcn_s_barrier();
  }
  COMPUTE(nt-3);
  asm volatile("s_waitcnt vmcnt(4)" ::: "memory");
  __builtin_amdgcn_s_barrier();
  COMPUTE(nt-2);
  asm volatile("s_waitcnt vmcnt(0)" ::: "memory");
  __builtin_amdgcn_s_barrier();
  COMPUTE(nt-1);

  const float SC2 = 0.125f * 1.44269504089f;
  #pragma unroll
  for (int mf=0;mf<8;++mf){
    int rowb = bm + wm*128 + mf*16 + g*4;
    #pragma unroll
    for (int nf=0;nf<4;++nf){
      int col = bn + wn*64 + nf*16 + lrow;
      float bv = bias[col];
      #pragma unroll
      for (int r=0;r<4;++r){
        float vv = acc[mf][nf][r] + bv;
        if constexpr (EPI==0){ if (col < 1024) vv *= SC2; }
        if constexpr (EPI==1){
          float ex = e2(-2.3022080654f*(vv + 0.044715f*vv*vv*vv));
          vv = vv * __builtin_amdgcn_rcpf(1.0f + ex);
        }
        Cp[(size_t)(rowb+r)*N + col] = f2b(vv);
      }
    }
  }
}

// ---------------- mid GEMM v3: 128x128 tile, BK=64, 8 waves, 4-deep ring (128KB), counted vmcnt ----------------
// For N=1024 shapes (proj, MLP2): grid 256 = 1 block/CU, 2 waves/SIMD. EPI: 2 = bias + f32 residual -> f32.
// 8 waves (2M x 4N), per-wave 64x32 output, acc[4][2]; two BK=32 sub-steps per iteration (no barrier between).
// Stage: slot = 16KB A + 16KB B; 512 threads x (2A + 2B) loads -> vmcnt ledger 8/4/0 (same as gemm256).
template<int EPI>
__global__ __launch_bounds__(512,1) void gemm128(const bf16* __restrict__ A, const bf16* __restrict__ Bt,
                                                 const float* __restrict__ bias, const float* __restrict__ res,
                                                 void* __restrict__ Cp, int M, int N, int K){
  extern __shared__ char lds[];
  const int t = threadIdx.x, lane = t & 63, w = t >> 6;
  const int wm = w >> 2, wn = w & 3;
  const int lrow = lane & 15, g = lane >> 4;
  const int sw = (lrow & 7) << 4;

  const int nwg = gridDim.x;
  int flat = blockIdx.x;
  int nb = (nwg & 7) ? flat : ((flat & 7)*(nwg>>3) + (flat>>3));
  const int nbx = N >> 7;
  const int bm = (nb / nbx) << 7, bn = (nb % nbx) << 7;

  f32x4 acc[4][2] = {};
  const int nt = K >> 6;

  // 128B rows (8 chunks); physical chunk p -> source (row r, slot sl) with sl = (p&7)^(r&7)
  int srcOff[2];
  #pragma unroll
  for (int i=0;i<2;++i){
    int p = t + i*512;
    int r = p >> 3;
    int sl = (p & 7) ^ (r & 7);
    srcOff[i] = r*K + sl*8;
  }

  auto STAGE = [&](int tt){
    char* sA = lds + (size_t)(tt&3)*32768;
    char* sB = sA + 16384;
    int k0 = tt << 6;
    #pragma unroll
    for (int i=0;i<2;++i){
      unsigned dst = (unsigned)(i*8192 + w*1024);
      gload_lds16(A  + (size_t)bm*K + srcOff[i] + k0, sA + dst);
      gload_lds16(Bt + (size_t)bn*K + srcOff[i] + k0, sB + dst);
    }
  };

  auto COMPUTE = [&](int tt){
    const char* sA = lds + (size_t)(tt&3)*32768;
    const char* sB = sA + 16384;
    #pragma unroll
    for (int ks=0; ks<2; ++ks){
      short8 af[4], bfr[2];
      #pragma unroll
      for (int mf=0;mf<4;++mf)
        af[mf] = *(const short8*)(sA + (((wm*64 + mf*16 + lrow)*128 + ks*64 + g*16) ^ sw));
      #pragma unroll
      for (int nf=0;nf<2;++nf)
        bfr[nf] = *(const short8*)(sB + (((wn*32 + nf*16 + lrow)*128 + ks*64 + g*16) ^ sw));
      __builtin_amdgcn_s_setprio(1);
      #pragma unroll
      for (int mf=0;mf<4;++mf)
        #pragma unroll
        for (int nf=0;nf<2;++nf)
          acc[mf][nf] = __builtin_amdgcn_mfma_f32_16x16x32_bf16(af[mf], bfr[nf], acc[mf][nf], 0,0,0);
      __builtin_amdgcn_s_setprio(0);
    }
  };

  STAGE(0); STAGE(1); STAGE(2);
  asm volatile("s_waitcnt vmcnt(8)" ::: "memory");
  __builtin_amdgcn_s_barrier();

  for (int tt=0; tt<nt-3; ++tt){
    STAGE(tt+3);
    COMPUTE(tt);
    asm volatile("s_waitcnt vmcnt(8)" ::: "memory");
    __builtin_amdgcn_s_barrier();
  }
  COMPUTE(nt-3);
  asm volatile("s_waitcnt vmcnt(4)" ::: "memory");
  __builtin_amdgcn_s_barrier();
  COMPUTE(nt-2);
  asm volatile("s_waitcnt vmcnt(0)" ::: "memory");
  __builtin_amdgcn_s_barrier();
  COMPUTE(nt-1);

  #pragma unroll
  for (int mf=0;mf<4;++mf){
    int rowb = bm + wm*64 + mf*16 + g*4;
    #pragma unroll
    for (int nf=0;nf<2;++nf){
      int col = bn + wn*32 + nf*16 + lrow;
      float bv = bias[col];
      #pragma unroll
      for (int r=0;r<4;++r){
        size_t idx = (size_t)(rowb+r)*N + col;
        float vv = acc[mf][nf][r] + bv;
        if constexpr (EPI==2){ vv += res[idx]; ((float*)Cp)[idx] = vv; }
        else ((bf16*)Cp)[idx] = f2b(vv);
      }
    }
  }
}

// ---------------- flash attention v8: swapped QK^T, STATIC softmax (m=0), in-reg P exchange ----------------
__global__ __launch_bounds__(512,4) void attn_k(const bf16* __restrict__ q, const bf16* __restrict__ k,
                                                const bf16* __restrict__ vT, bf16* __restrict__ o, int ldq){
  __shared__ char Ks[2][8192];
  __shared__ char Vs[2][8192];

  int flat = blockIdx.x;
  int xs = flat & 7, j = flat >> 3;
  int bh = xs*4 + (j & 3), qt = j >> 2;
  int b = bh >> 4, h = bh & 15;
  int t = threadIdx.x, lane = t & 63, w = t >> 6;
  int lrow = lane & 15, g = lane >> 4, lko = g*8;

  const bf16* kbase = k  + (size_t)b*2048*ldq + h*64;
  const bf16* vtb   = vT + (size_t)bh*64*2048;

  size_t qrow = (size_t)(b*2048 + qt*128 + w*16 + lrow);
  short8 qf0 = *(const short8*)(q + qrow*ldq + h*64 + lko);
  short8 qf1 = *(const short8*)(q + qrow*ldq + h*64 + 32 + lko);

  int srow = t >> 3, scolb = (t & 7) << 4;
  int ssw = scolb ^ ((srow & 7) << 4);
  const bf16* ksrc = kbase + (size_t)srow*ldq + (ssw >> 1);
  const bf16* vsrc = vtb   + (size_t)srow*2048 + (ssw >> 1);
  unsigned ldst = (unsigned)(w*64*16);

  const short8 onesf = {0x3F80,0x3F80,0x3F80,0x3F80,0x3F80,0x3F80,0x3F80,0x3F80};

  const int srcU = lrow + ((2*(g&1) + (g>>1)) << 4);
  const int srcV = lrow + ((2*(g&1) + 1 - (g>>1)) << 4);
  const bool gOdd = (g & 1), lo = ((g>>1) == 0);

  f32x4 lacc = {};
  f32x4 oacc[4] = {};
  const int sw = (lrow & 7) << 4;

  gload_lds16(ksrc, Ks[0] + ldst);
  gload_lds16(vsrc, Vs[0] + ldst);
  __syncthreads();

  int cur = 0;
  for (int tile = 0; tile < 32; ++tile){
    int kt = tile*64;
    if (tile < 31){
      gload_lds16(ksrc + (size_t)(kt+64)*ldq, Ks[cur^1] + ldst);
      gload_lds16(vsrc + (kt+64),             Vs[cur^1] + ldst);
    }

    f32x4 s[4];
    __builtin_amdgcn_s_setprio(1);
    #pragma unroll
    for (int cb=0; cb<4; ++cb){
      const char* kp = Ks[cur] + (cb*16 + lrow)*128;
      short8 kf0 = *(const short8*)(kp + ((g*16) ^ sw));
      short8 kf1 = *(const short8*)(kp + ((64 + g*16) ^ sw));
      f32x4 a = {};
      a = __builtin_amdgcn_mfma_f32_16x16x32_bf16(kf0, qf0, a, 0,0,0);
      a = __builtin_amdgcn_mfma_f32_16x16x32_bf16(kf1, qf1, a, 0,0,0);
      s[cb] = a;
    }
    __builtin_amdgcn_s_setprio(0);

    // static softmax: P = exp2(s), no running max, no rescale
    unsigned pA0 = pk2(e2(s[0][0]), e2(s[0][1]));
    unsigned pB0 = pk2(e2(s[0][2]), e2(s[0][3]));
    unsigned pA1 = pk2(e2(s[1][0]), e2(s[1][1]));
    unsigned pB1 = pk2(e2(s[1][2]), e2(s[1][3]));
    unsigned pA2 = pk2(e2(s[2][0]), e2(s[2][1]));
    unsigned pB2 = pk2(e2(s[2][2]), e2(s[2][3]));
    unsigned pA3 = pk2(e2(s[3][0]), e2(s[3][1]));
    unsigned pB3 = pk2(e2(s[3][2]), e2(s[3][3]));

    unsigned ruA = __shfl((int)(gOdd?pA1:pA0), srcU, 64);
    unsigned rvA = __shfl((int)(gOdd?pA0:pA1), srcV, 64);
    unsigned ruB = __shfl((int)(gOdd?pB1:pB0), srcU, 64);
    unsigned rvB = __shfl((int)(gOdd?pB0:pB1), srcV, 64);
    unsigned ruA2= __shfl((int)(gOdd?pA3:pA2), srcU, 64);
    unsigned rvA2= __shfl((int)(gOdd?pA2:pA3), srcV, 64);
    unsigned ruB2= __shfl((int)(gOdd?pB3:pB2), srcU, 64);
    unsigned rvB2= __shfl((int)(gOdd?pB2:pB3), srcV, 64);

    u32x4 w0 = { lo?ruA:rvA,  lo?ruB:rvB,  lo?rvA:ruA,  lo?rvB:ruB  };
    u32x4 w1 = { lo?ruA2:rvA2,lo?ruB2:rvB2,lo?rvA2:ruA2,lo?rvB2:ruB2};
    short8 pf0 = __builtin_bit_cast(short8, w0);
    short8 pf1 = __builtin_bit_cast(short8, w1);

    __builtin_amdgcn_s_setprio(1);
    lacc = __builtin_amdgcn_mfma_f32_16x16x32_bf16(pf0, onesf, lacc, 0,0,0);
    lacc = __builtin_amdgcn_mfma_f32_16x16x32_bf16(pf1, onesf, lacc, 0,0,0);
    #pragma unroll
    for (int half=0; half<2; ++half){
      short8 pf = half ? pf1 : pf0;
      #pragma unroll
      for (int db=0; db<4; ++db){
        const char* vp = Vs[cur] + (db*16 + lrow)*128;
        short8 vf = *(const short8*)(vp + ((half*64 + g*16) ^ sw));
        oacc[db] = __builtin_amdgcn_mfma_f32_16x16x32_bf16(pf, vf, oacc[db], 0,0,0);
      }
    }
    __builtin_amdgcn_s_setprio(0);
    __syncthreads();
    cur ^= 1;
  }

  f32x4 inv;
  #pragma unroll
  for (int r=0;r<4;++r) inv[r] = 1.0f/lacc[r];
  size_t obase = ((size_t)(b*2048 + qt*128 + w*16))*1024 + h*64;
  #pragma unroll
  for (int db=0; db<4; ++db)
    #pragma unroll
    for (int r=0;r<4;++r)
      o[obase + (size_t)(g*4+r)*1024 + db*16 + lrow] = f2b(oacc[db][r] * inv[r]);
}

// ---------------- launch ----------------
extern "C" void kernel_launch(void* const* d_in, const int* in_sizes, int n_in,
                              void* d_out, int out_size, void* d_ws, size_t ws_size,
                              hipStream_t stream) {
  (void)in_sizes; (void)n_in; (void)out_size; (void)ws_size;
  const float* x    = (const float*)d_in[0];
  const float* ln1w = (const float*)d_in[1];
  const float* ln1b = (const float*)d_in[2];
  const float* ln2w = (const float*)d_in[3];
  const float* ln2b = (const float*)d_in[4];
  const float* wq   = (const float*)d_in[5];
  const float* bq   = (const float*)d_in[6];
  const float* wk   = (const float*)d_in[7];
  const float* bk   = (const float*)d_in[8];
  const float* wv   = (const float*)d_in[9];
  const float* bv   = (const float*)d_in[10];
  const float* wo   = (const float*)d_in[11];
  const float* bo   = (const float*)d_in[12];
  const float* w1   = (const float*)d_in[13];
  const float* b1   = (const float*)d_in[14];
  const float* w2   = (const float*)d_in[15];
  const float* b2   = (const float*)d_in[16];

  char* ws = (char*)d_ws;
  const size_t MB = 1u<<20;
  bf16* wqkvT = (bf16*)(ws + 0*MB);   // [3072,1024] bf16
  bf16* woT   = (bf16*)(ws + 6*MB);
  bf16* w1T   = (bf16*)(ws + 8*MB);   // [4096,1024]
  bf16* w2T   = (bf16*)(ws + 16*MB);  // [1024,4096]
  bf16* qkv   = (bf16*)(ws + 24*MB);  // [4096,3072] bf16 = 24 MB
  bf16* ao    = (bf16*)(ws + 48*MB);  // [4096,1024] bf16 = 8 MB
  bf16* vT    = (bf16*)(ws + 56*MB);  // 8 MB, alive only during attn
  float* x1   = (float*)(ws + 56*MB); // 16 MB f32, written after attn
  bf16* lnb   = (bf16*)(ws + 72*MB);  // 8 MB
  bf16* h1    = (bf16*)(ws + 24*MB);  // [4096,4096] bf16 = 32 MB, reuse qkv+ao after proj
  float* bqkv = (float*)(ws + 80*MB); // 12 KB

  hipMemcpyAsync(bqkv,        bq, 1024*sizeof(float), hipMemcpyDeviceToDevice, stream);
  hipMemcpyAsync(bqkv + 1024, bk, 1024*sizeof(float), hipMemcpyDeviceToDevice, stream);
  hipMemcpyAsync(bqkv + 2048, bv, 1024*sizeof(float), hipMemcpyDeviceToDevice, stream);

  dim3 tpb(32,8);
  transpose_k<<<dim3(32,32),  tpb,0,stream>>>(wq, wqkvT,            1024,1024);
  transpose_k<<<dim3(32,32),  tpb,0,stream>>>(wk, wqkvT + 1024*1024,1024,1024);
  transpose_k<<<dim3(32,32),  tpb,0,stream>>>(wv, wqkvT + 2048*1024,1024,1024);
  transpose_k<<<dim3(32,32),  tpb,0,stream>>>(wo, woT, 1024,1024);
  transpose_k<<<dim3(128,32), tpb,0,stream>>>(w1, w1T, 1024,4096);
  transpose_k<<<dim3(32,128), tpb,0,stream>>>(w2, w2T, 4096,1024);

  ln_k<<<4096,256,0,stream>>>(x, ln1w, ln1b, lnb);
  gemm256<0><<<192,512,131072,stream>>>(lnb, wqkvT, bqkv, qkv, 4096,3072,1024);
  vtrans_k<<<dim3(64,2,32),tpb,0,stream>>>(qkv + 2048, vT, 3072);
  attn_k<<<512,512,0,stream>>>(qkv, qkv + 1024, vT, ao, 3072);
  gemm128<2><<<256,512,131072,stream>>>(ao, woT, bo, x, x1, 4096,1024,1024);
  ln_k<<<4096,256,0,stream>>>(x1, ln2w, ln2b, lnb);
  gemm256<1><<<256,512,131072,stream>>>(lnb, w1T, b1, h1, 4096,4096,1024);
  gemm128<2><<<256,512,131072,stream>>>(h1, w2T, b2, x1, (float*)d_out, 4096,1024,4096);
}